// Round 3
// baseline (162.698 us; speedup 1.0000x reference)
//
#include <hip/hip_runtime.h>

#define ROWS   32768      // 8*4096 indices
#define DIM4   128        // 512 floats per row = 128 float4
#define BLOCK  256
#define TPR    16         // threads per row; each thread: 8 float4 (128B) at cols c, c+16, ..., c+112

typedef float f4 __attribute__((ext_vector_type(4)));

__global__ __launch_bounds__(BLOCK) void embed_gather_kernel(
    const int* __restrict__ idx,
    const f4* __restrict__ W,
    f4* __restrict__ out)
{
    const int t   = blockIdx.x * BLOCK + threadIdx.x;
    const int row = t >> 4;          // 16 threads per output row
    const int c   = t & 15;          // base col in float4 units

    const int id  = idx[row];        // one dependent scalar-ish load per thread

    const f4* __restrict__ src = W   + (size_t)id  * DIM4 + c;
    f4*       __restrict__ dst = out + (size_t)row * DIM4 + c;

    // 8 independent 16B loads in flight per thread (MLP=8) before any store.
    // Per instruction a wave covers 4 contiguous 256B segments (4 rows/wave).
    f4 v0 = src[0];
    f4 v1 = src[16];
    f4 v2 = src[32];
    f4 v3 = src[48];
    f4 v4 = src[64];
    f4 v5 = src[80];
    f4 v6 = src[96];
    f4 v7 = src[112];

    // out is write-once streaming: keep it out of L2 so W row-repeats stay cached.
    __builtin_nontemporal_store(v0, dst);
    __builtin_nontemporal_store(v1, dst + 16);
    __builtin_nontemporal_store(v2, dst + 32);
    __builtin_nontemporal_store(v3, dst + 48);
    __builtin_nontemporal_store(v4, dst + 64);
    __builtin_nontemporal_store(v5, dst + 80);
    __builtin_nontemporal_store(v6, dst + 96);
    __builtin_nontemporal_store(v7, dst + 112);
}

extern "C" void kernel_launch(void* const* d_in, const int* in_sizes, int n_in,
                              void* d_out, int out_size, void* d_ws, size_t ws_size,
                              hipStream_t stream) {
    const int* idx = (const int*)d_in[0];
    const f4*  W   = (const f4*)d_in[1];
    f4*        out = (f4*)d_out;

    const int grid = ROWS * TPR / BLOCK;      // 2048 blocks = 8192 waves = exactly 32 waves/CU
    embed_gather_kernel<<<grid, BLOCK, 0, stream>>>(idx, W, out);
}